// Round 2
// baseline (320.147 us; speedup 1.0000x reference)
//
#include <hip/hip_runtime.h>
#include <math.h>

// DigitCaps dynamic routing, B=256 R=1152 C=10 OUT=16 IN=8, fp32.
// b_ij(t) = dot(u_hat, Vsum) with Vsum = sum of previous v iterates ->
// never store b_ij or u_hat; recompute u_hat per iteration from W (LDS-staged).
//
// This round: Tb=4 batches/thread + o-split (2 threads share the 16 o's),
// register double-buffered W staging, conflict-free Lg/Vsl padding.
//
// ws: s_part[36][256][160] f32 (5.90 MB) + Vsum[256][160] f32 (0.16 MB)

namespace {
constexpr int Bdim = 256;
constexpr int Rdim = 1152;
constexpr int Cdim = 10;
constexpr int Odim = 16;
constexpr int Idim = 8;
constexpr int CO   = Cdim * Odim;   // 160

constexpr int NCH  = 36;            // r-chunks
constexpr int RSUB = 8;             // rows staged per sub-step
constexpr int NSUB = 4;             // subs per chunk (32 rows)
constexpr int BB   = 8;             // batches per block (2 bq * 4 t)
constexpr int NT   = 320;           // 5 waves: 2 bq * 10 c * 8 rl * 2 oh
constexpr int WSL  = 33;            // float4 slots per (r,c) slice (32+1 pad)
constexpr int LGP  = 12;            // Lg row pad (rl stride 12 -> 8 banks)
constexpr int VSP  = 20;            // Vsl (b,c) row pad (c stride 20 -> 8 groups)
}

template<bool FIRST>
__global__ __launch_bounds__(NT, 3)
void caps_iter(const float* __restrict__ x, const float* __restrict__ W,
               const float* __restrict__ Vsum, float* __restrict__ s_part)
{
    __shared__ __align__(16) float4 Wl[RSUB * Cdim * WSL];   // 42.24 KB
    __shared__ __align__(16) float  Lg[2 * 4 * RSUB * LGP];  // 3 KB
    __shared__ __align__(16) float  Vsl[BB * Cdim * VSP];    // 6.4 KB

    const int tid = threadIdx.x;
    const int bq  = tid / 160;            // 0..1
    const int rem = tid - bq * 160;
    const int c   = rem >> 4;             // 0..9
    const int rl  = (rem >> 1) & 7;       // 0..7 (lane bits 1..3)
    const int oh  = rem & 1;              // 0..1 (lane bit 0)

    const int chunk = blockIdx.x;                 // 0..35
    const int bbase = blockIdx.y * BB;            // step 8
    const int b0    = bbase + bq * 4;             // 4 batches: b0..b0+3

    if (!FIRST) {
        for (int t = tid; t < BB * CO; t += NT) {
            const int b  = t / CO;
            const int r2 = t - b * CO;
            const int cc = r2 >> 4;
            const int oo = r2 & 15;
            Vsl[(b * Cdim + cc) * VSP + oo] = Vsum[bbase * CO + t];
        }
    }

    // stage addressing: k-th load: global f4 idx (r0+k)*320 + (tid>>5)*32 + (tid&31)
    //                   LDS slot (k*10 + (tid>>5))*33 + (tid&31)
    const int cc0 = tid >> 5;
    const int w0  = tid & 31;

    float4 st[8];
    {   // prologue: stage sub 0
        const float4* Wg = reinterpret_cast<const float4*>(W)
                         + (size_t)(chunk * (RSUB * NSUB)) * 320;
#pragma unroll
        for (int k = 0; k < 8; ++k) st[k] = Wg[tid + 320 * k];
#pragma unroll
        for (int k = 0; k < 8; ++k) Wl[(k * Cdim + cc0) * WSL + w0] = st[k];
    }
    __syncthreads();

    float s[4][8];
#pragma unroll
    for (int t = 0; t < 4; ++t)
#pragma unroll
        for (int ol = 0; ol < 8; ++ol) s[t][ol] = 0.f;

    for (int sub = 0; sub < NSUB; ++sub) {
        // issue next sub's global loads early (latency hides under compute)
        if (sub < NSUB - 1) {
            const float4* Wg = reinterpret_cast<const float4*>(W)
                             + (size_t)(chunk * (RSUB * NSUB) + (sub + 1) * RSUB) * 320;
#pragma unroll
            for (int k = 0; k < 8; ++k) st[k] = Wg[tid + 320 * k];
        }

        const int r = chunk * (RSUB * NSUB) + sub * RSUB + rl;

        // x[b, r, 0..7] for 4 batches
        float4 xa[4], xb[4];
#pragma unroll
        for (int t = 0; t < 4; ++t) {
            const float4* xp = reinterpret_cast<const float4*>(
                x + ((size_t)(b0 + t) * Rdim + r) * Idim);
            xa[t] = xp[0]; xb[t] = xp[1];
        }

        // u[t][ol] for o = oh*8 + ol
        float u[4][8];
        const float4* wp = Wl + (rl * Cdim + c) * WSL + oh * 16;
#pragma unroll
        for (int ol = 0; ol < 8; ++ol) {
            const float4 wa = wp[2 * ol];
            const float4 wb = wp[2 * ol + 1];
#pragma unroll
            for (int t = 0; t < 4; ++t) {
                u[t][ol] = wa.x * xa[t].x + wa.y * xa[t].y + wa.z * xa[t].z + wa.w * xa[t].w
                         + wb.x * xb[t].x + wb.y * xb[t].y + wb.z * xb[t].z + wb.w * xb[t].w;
            }
        }

        float cw[4];
        if (FIRST) {
#pragma unroll
            for (int t = 0; t < 4; ++t) cw[t] = 0.1f;   // softmax of zeros
        } else {
            float l[4];
#pragma unroll
            for (int t = 0; t < 4; ++t) {
                const float4* vp = reinterpret_cast<const float4*>(
                    Vsl + ((bq * 4 + t) * Cdim + c) * VSP + oh * 8);
                const float4 v0 = vp[0], v1 = vp[1];
                float lt = u[t][0] * v0.x + u[t][1] * v0.y + u[t][2] * v0.z + u[t][3] * v0.w
                         + u[t][4] * v1.x + u[t][5] * v1.y + u[t][6] * v1.z + u[t][7] * v1.w;
                lt += __shfl_xor(lt, 1);        // combine o-halves
                l[t] = lt;
            }
            if (oh == 0) {
#pragma unroll
                for (int t = 0; t < 4; ++t)
                    Lg[((bq * 4 + t) * RSUB + rl) * LGP + c] = l[t];
            }
            __syncthreads();
#pragma unroll
            for (int t = 0; t < 4; ++t) {
                const float* lp = Lg + ((bq * 4 + t) * RSUB + rl) * LGP;
                float m = -1e30f;
#pragma unroll
                for (int cc = 0; cc < Cdim; ++cc) m = fmaxf(m, lp[cc]);
                float d = 0.f;
#pragma unroll
                for (int cc = 0; cc < Cdim; ++cc) d += __expf(lp[cc] - m);
                cw[t] = __expf(l[t] - m) / d;
            }
        }

#pragma unroll
        for (int t = 0; t < 4; ++t)
#pragma unroll
            for (int ol = 0; ol < 8; ++ol) s[t][ol] += cw[t] * u[t][ol];

        if (sub < NSUB - 1) {
            __syncthreads();   // Wl + Lg reads of this sub done
#pragma unroll
            for (int k = 0; k < 8; ++k) Wl[(k * Cdim + cc0) * WSL + w0] = st[k];
            __syncthreads();   // new Wl visible
        }
    }

    // reduce over rl (lane bits 1..3)
#pragma unroll
    for (int t = 0; t < 4; ++t)
#pragma unroll
        for (int ol = 0; ol < 8; ++ol) {
            float v = s[t][ol];
            v += __shfl_xor(v, 2);
            v += __shfl_xor(v, 4);
            v += __shfl_xor(v, 8);
            s[t][ol] = v;
        }

    if (rl == 0) {
#pragma unroll
        for (int t = 0; t < 4; ++t) {
            float* dst = s_part + ((size_t)chunk * Bdim + (b0 + t)) * CO
                       + c * Odim + oh * 8;
            reinterpret_cast<float4*>(dst)[0] =
                make_float4(s[t][0], s[t][1], s[t][2], s[t][3]);
            reinterpret_cast<float4*>(dst)[1] =
                make_float4(s[t][4], s[t][5], s[t][6], s[t][7]);
        }
    }
}

// Sum the NCH partials, squash, then either accumulate Vsum or emit output.
template<bool LAST>
__global__ __launch_bounds__(256)
void caps_reduce(const float* __restrict__ s_part, float* __restrict__ Vsum,
                 float* __restrict__ out)
{
    const int idx = blockIdx.x * 256 + threadIdx.x;   // < 40960 = B*C*O
    float s = 0.f;
#pragma unroll 4
    for (int k = 0; k < NCH; ++k) s += s_part[(size_t)k * (Bdim * CO) + idx];

    // ||s||^2 over the 16-lane o-group
    float ssq = s * s;
    ssq += __shfl_xor(ssq, 1);
    ssq += __shfl_xor(ssq, 2);
    ssq += __shfl_xor(ssq, 4);
    ssq += __shfl_xor(ssq, 8);

    const float mag = sqrtf(ssq + 1e-8f);
    const float v = ssq / (1.f + ssq) * s / (mag + 1e-8f);

    if (LAST) out[idx] = v;
    else      Vsum[idx] += v;
}

extern "C" void kernel_launch(void* const* d_in, const int* in_sizes, int n_in,
                              void* d_out, int out_size, void* d_ws, size_t ws_size,
                              hipStream_t stream)
{
    const float* x = (const float*)d_in[0];   // [256,1152,8]
    const float* W = (const float*)d_in[1];   // [1152,10,16,8]
    float* out = (float*)d_out;               // [256,10,16]

    float* s_part = (float*)d_ws;                       // 36*256*160 f32
    float* Vsum   = s_part + (size_t)NCH * Bdim * CO;   // 256*160 f32

    hipMemsetAsync(Vsum, 0, (size_t)Bdim * CO * sizeof(float), stream);

    const dim3 gi(NCH, Bdim / BB);
    const dim3 bi(NT);
    const dim3 gr((Bdim * CO) / 256);
    const dim3 br(256);

    // it 0
    caps_iter<true><<<gi, bi, 0, stream>>>(x, W, Vsum, s_part);
    caps_reduce<false><<<gr, br, 0, stream>>>(s_part, Vsum, out);
    // it 1
    caps_iter<false><<<gi, bi, 0, stream>>>(x, W, Vsum, s_part);
    caps_reduce<false><<<gr, br, 0, stream>>>(s_part, Vsum, out);
    // it 2 (final -> d_out)
    caps_iter<false><<<gi, bi, 0, stream>>>(x, W, Vsum, s_part);
    caps_reduce<true><<<gr, br, 0, stream>>>(s_part, Vsum, out);
}

// Round 3
// 168.319 us; speedup vs baseline: 1.9020x; 1.9020x over previous
//
#include <hip/hip_runtime.h>
#include <math.h>

// DigitCaps dynamic routing, B=256 R=1152 C=10 OUT=16 IN=8, fp32.
// Identity: b_ij(t) = dot(u_hat, Vsum), Vsum = sum of previous v iterates ->
// never store b_ij or u_hat; recompute u_hat each iteration from W.
//
// Structure: W staged global->LDS via __builtin_amdgcn_global_load_lds (16B),
// double-buffered, counted vmcnt + raw s_barrier (loads stay in flight).
// LDS dest is linear (HW requirement) -> bank conflicts fixed by XOR-swizzling
// the per-lane GLOBAL source address and applying the same XOR on ds_read.
// Wave layout: lane = oh(1)|rl(2)|bq(2)|ch(1), wave = cw (c = ch*5+cw).
// v held in registers; softmax exchange via small Lg buffer + shuffles.
//
// ws: s_part[32][256][160] f32 (5.24 MB) + Vsum[256][160] f32 (0.16 MB)

namespace {
constexpr int Bdim = 256;
constexpr int Rdim = 1152;
constexpr int Cdim = 10;
constexpr int CO   = 160;

constexpr int NCH  = 32;   // r-chunks
constexpr int ROWS = 36;   // rows per chunk
constexpr int RSUB = 4;    // rows staged per sub-step
constexpr int NSUB = 9;    // subs per chunk
constexpr int BB   = 8;    // batches per block (4 bq * 2 t)
constexpr int NT   = 320;  // 5 waves
}

// Stage 4 W rows (1280 float4) into linear LDS, source pre-swizzled so that
// physical slot (slice, oh*16 + w) holds logical f4 (oh*16 + (w ^ (2*rr+oh))).
__device__ __forceinline__ void stage4(const float4* __restrict__ Wg4, float4* dst,
                                       int row0, int tid)
{
#pragma unroll
    for (int k = 0; k < 4; ++k) {
        const int p   = k * NT + tid;          // physical f4 position 0..1279
        const int s   = p >> 5;                // slice = rr*10 + cs
        const int q   = p & 31;
        const int ohs = (q >> 4) & 1;
        const int w   = q & 15;
        const int rr  = s / 10;
        const int cs  = s - rr * 10;
        const int prm = rr * 2 + ohs;          // 0..7
        const float4* src = Wg4 + ((size_t)(row0 + rr) * 320 + cs * 32 + ohs * 16 + (w ^ prm));
        float4* d = dst + (k * NT + (tid & ~63));   // wave-uniform base; HW adds lane*16
        __builtin_amdgcn_global_load_lds((const __attribute__((address_space(1))) void*)src,
                                         (__attribute__((address_space(3))) void*)d,
                                         16, 0, 0);
    }
}

template<bool FIRST>
__global__ __launch_bounds__(NT)
void caps_iter(const float* __restrict__ x, const float* __restrict__ W,
               const float* __restrict__ Vsum, float* __restrict__ s_part)
{
    __shared__ float4 Wb[2][RSUB * Cdim * 32];   // 2 x 20 KB, linear
    __shared__ float  Lg[BB * RSUB * 13];        // 1.7 KB logit exchange

    const int tid  = threadIdx.x;
    const int lane = tid & 63;
    const int oh   = lane & 1;          // o-half
    const int rl   = (lane >> 1) & 3;   // row within sub
    const int bq   = (lane >> 3) & 3;   // batch pair
    const int ch   = (lane >> 5) & 1;   // c-half
    const int cw   = tid >> 6;          // wave 0..4
    const int c    = ch * 5 + cw;

    const int bgrp  = blockIdx.x;
    const int chunk = blockIdx.y;
    const int bbase = bgrp * BB;
    const int b0    = bbase + bq * 2;   // this thread's batches: b0, b0+1

    const float4* Wg4 = reinterpret_cast<const float4*>(W);
    const float4* Xg4 = reinterpret_cast<const float4*>(x);

    // v (= Vsum) in registers for this thread's (b0,b0+1, c, o-half)
    float4 va0, vb0, va1, vb1;
    if (!FIRST) {
        const float4* Vg = reinterpret_cast<const float4*>(Vsum)
                         + ((size_t)b0 * 40 + c * 4 + oh * 2);
        va0 = Vg[0];  vb0 = Vg[1];
        va1 = Vg[40]; vb1 = Vg[41];
    }

    stage4(Wg4, &Wb[0][0], chunk * ROWS, tid);   // prologue: sub 0

    float s0[8], s1[8];
#pragma unroll
    for (int m = 0; m < 8; ++m) { s0[m] = 0.f; s1[m] = 0.f; }

    const int perm = rl * 2 + oh;
    int cur = 0;

    for (int sub = 0; sub < NSUB; ++sub) {
        const int r = chunk * ROWS + sub * RSUB + rl;

        // x[b, r, 0..7] for both batches (issued early; L1-resident)
        const float4* xp0 = Xg4 + ((size_t)b0 * Rdim + r) * 2;
        const float4 xa0 = xp0[0], xb0 = xp0[1];
        const float4 xa1 = xp0[Rdim * 2], xb1 = xp0[Rdim * 2 + 1];
        asm volatile("" ::: "memory");

        if (sub + 1 < NSUB) {
            stage4(Wg4, &Wb[cur ^ 1][0], chunk * ROWS + (sub + 1) * RSUB, tid);
            asm volatile("s_waitcnt vmcnt(8) lgkmcnt(0)" ::: "memory");  // prev stage done
        } else {
            asm volatile("s_waitcnt vmcnt(4) lgkmcnt(0)" ::: "memory");
        }
        __builtin_amdgcn_s_barrier();            // HEAD: Wb[cur] ready block-wide
        asm volatile("" ::: "memory");

        // u[t][m] for o = oh*8 + m, from swizzled LDS
        const float4* wp = &Wb[cur][(rl * Cdim + c) * 32 + oh * 16];
        float u0[8], u1[8];
#pragma unroll
        for (int m = 0; m < 8; ++m) {
            const float4 wa = wp[(2 * m) ^ perm];
            const float4 wb = wp[(2 * m + 1) ^ perm];
            u0[m] = wa.x * xa0.x + wa.y * xa0.y + wa.z * xa0.z + wa.w * xa0.w
                  + wb.x * xb0.x + wb.y * xb0.y + wb.z * xb0.z + wb.w * xb0.w;
            u1[m] = wa.x * xa1.x + wa.y * xa1.y + wa.z * xa1.z + wa.w * xa1.w
                  + wb.x * xb1.x + wb.y * xb1.y + wb.z * xb1.z + wb.w * xb1.w;
        }

        float cw0, cw1;
        if (FIRST) {
            cw0 = 0.1f; cw1 = 0.1f;              // softmax of zeros over C=10
        } else {
            float l0 = u0[0]*va0.x + u0[1]*va0.y + u0[2]*va0.z + u0[3]*va0.w
                     + u0[4]*vb0.x + u0[5]*vb0.y + u0[6]*vb0.z + u0[7]*vb0.w;
            float l1 = u1[0]*va1.x + u1[1]*va1.y + u1[2]*va1.z + u1[3]*va1.w
                     + u1[4]*vb1.x + u1[5]*vb1.y + u1[6]*vb1.z + u1[7]*vb1.w;
            l0 += __shfl_xor(l0, 1);             // combine o-halves
            l1 += __shfl_xor(l1, 1);

            // lane oh writes its t=oh row entry
            const int myrow = (bq * 2 + oh) * RSUB + rl;
            Lg[myrow * 13 + c] = oh ? l1 : l0;
            asm volatile("s_waitcnt lgkmcnt(0)" ::: "memory");
            __builtin_amdgcn_s_barrier();        // BARRIER2 (doubles as tail barrier)
            asm volatile("" ::: "memory");

            // lane (ch,oh) reads 5 of the 10 logits of row t=oh; combine by shuffle
            const float* lp = &Lg[myrow * 13 + ch * 5];
            const float a0 = lp[0], a1 = lp[1], a2 = lp[2], a3 = lp[3], a4 = lp[4];
            float pm = fmaxf(fmaxf(fmaxf(a0, a1), fmaxf(a2, a3)), a4);
            pm = fmaxf(pm, __shfl_xor(pm, 32));  // full max over 10
            float pd = __expf(a0 - pm) + __expf(a1 - pm) + __expf(a2 - pm)
                     + __expf(a3 - pm) + __expf(a4 - pm);
            pd += __shfl_xor(pd, 32);            // full denom
            const float mo = __shfl_xor(pm, 1);  // partner t's (m,d)
            const float dd = __shfl_xor(pd, 1);
            const float m0 = oh ? mo : pm, d0 = oh ? dd : pd;
            const float m1 = oh ? pm : mo, d1 = oh ? pd : dd;
            cw0 = __expf(l0 - m0) / d0;
            cw1 = __expf(l1 - m1) / d1;
        }

#pragma unroll
        for (int m = 0; m < 8; ++m) { s0[m] += cw0 * u0[m]; s1[m] += cw1 * u1[m]; }

        if (FIRST && (sub + 1 < NSUB)) {         // tail barrier (non-FIRST: BARRIER2 covers)
            asm volatile("s_waitcnt lgkmcnt(0)" ::: "memory");
            __builtin_amdgcn_s_barrier();
            asm volatile("" ::: "memory");
        }
        cur ^= 1;
    }

    // reduce over rl (lane bits 1..2)
#pragma unroll
    for (int m = 0; m < 8; ++m) {
        float v0 = s0[m], v1 = s1[m];
        v0 += __shfl_xor(v0, 2); v0 += __shfl_xor(v0, 4);
        v1 += __shfl_xor(v1, 2); v1 += __shfl_xor(v1, 4);
        s0[m] = v0; s1[m] = v1;
    }

    if (rl == 0) {
        float* dst0 = s_part + (((size_t)chunk * Bdim + b0) * CO + c * 16 + oh * 8);
        reinterpret_cast<float4*>(dst0)[0] = make_float4(s0[0], s0[1], s0[2], s0[3]);
        reinterpret_cast<float4*>(dst0)[1] = make_float4(s0[4], s0[5], s0[6], s0[7]);
        float* dst1 = dst0 + CO;
        reinterpret_cast<float4*>(dst1)[0] = make_float4(s1[0], s1[1], s1[2], s1[3]);
        reinterpret_cast<float4*>(dst1)[1] = make_float4(s1[4], s1[5], s1[6], s1[7]);
    }
}

// Sum the NCH partials, squash, then either accumulate Vsum or emit output.
template<bool LAST>
__global__ __launch_bounds__(256)
void caps_reduce(const float* __restrict__ s_part, float* __restrict__ Vsum,
                 float* __restrict__ out)
{
    const int idx = blockIdx.x * 256 + threadIdx.x;   // < 40960 = B*C*O
    float s = 0.f;
#pragma unroll 8
    for (int k = 0; k < NCH; ++k) s += s_part[(size_t)k * (Bdim * CO) + idx];

    // ||s||^2 over the 16-lane o-group
    float ssq = s * s;
    ssq += __shfl_xor(ssq, 1);
    ssq += __shfl_xor(ssq, 2);
    ssq += __shfl_xor(ssq, 4);
    ssq += __shfl_xor(ssq, 8);

    const float mag = sqrtf(ssq + 1e-8f);
    const float v = ssq / (1.f + ssq) * s / (mag + 1e-8f);

    if (LAST) out[idx] = v;
    else      Vsum[idx] += v;
}

extern "C" void kernel_launch(void* const* d_in, const int* in_sizes, int n_in,
                              void* d_out, int out_size, void* d_ws, size_t ws_size,
                              hipStream_t stream)
{
    const float* x = (const float*)d_in[0];   // [256,1152,8]
    const float* W = (const float*)d_in[1];   // [1152,10,16,8]
    float* out = (float*)d_out;               // [256,10,16]

    float* s_part = (float*)d_ws;                       // 32*256*160 f32
    float* Vsum   = s_part + (size_t)NCH * Bdim * CO;   // 256*160 f32

    hipMemsetAsync(Vsum, 0, (size_t)Bdim * CO * sizeof(float), stream);

    const dim3 gi(Bdim / BB, NCH);   // b-group fastest -> same-chunk blocks share XCD L2
    const dim3 bi(NT);
    const dim3 gr((Bdim * CO) / 256);
    const dim3 br(256);

    // it 0
    caps_iter<true><<<gi, bi, 0, stream>>>(x, W, Vsum, s_part);
    caps_reduce<false><<<gr, br, 0, stream>>>(s_part, Vsum, out);
    // it 1
    caps_iter<false><<<gi, bi, 0, stream>>>(x, W, Vsum, s_part);
    caps_reduce<false><<<gr, br, 0, stream>>>(s_part, Vsum, out);
    // it 2 (final -> d_out)
    caps_iter<false><<<gi, bi, 0, stream>>>(x, W, Vsum, s_part);
    caps_reduce<true><<<gr, br, 0, stream>>>(s_part, Vsum, out);
}

// Round 6
// 118.347 us; speedup vs baseline: 2.7052x; 1.4223x over previous
//
#include <hip/hip_runtime.h>
#include <math.h>

// DigitCaps dynamic routing, B=256 R=1152 C=10 OUT=16 IN=8, fp32 in/out.
// Identity: b_ij(t) = dot(u_hat, Vsum), Vsum = sum of previous v iterates ->
// never store b_ij or u_hat; recompute u_hat each iteration from W.
//
// W pre-converted to f16 (ws), u_hat via v_dot2_f32_f16 (f32 acc),
// 4 batches/thread, ONE barrier per sub. RACE FIX vs previous round: the
// double-buffer re-stage is issued AFTER the head barrier (readers of that
// buffer drained by lgkmcnt(0) before it), so stage never overlaps live reads.
// Uniform wait: vmcnt(8) (= keep 8 x-loads in flight, drain the 2 stage loads)
// + lgkmcnt(0) before every barrier.
// LDS swizzle: XOR o-granule with perm=rl*2+oh on BOTH the pre-swizzled global
// source (gload_lds is linear-dest) and the ds_read -> conflict-free.
//
// ws: s_part[32][256][160] f32 (5.24 MB) + Vsum[256][160] f32 (0.16 MB)
//     + W16[1152][10][16][8] f16 (2.95 MB)  => 8.36 MB total

typedef _Float16 h2 __attribute__((ext_vector_type(2)));
typedef _Float16 h4 __attribute__((ext_vector_type(4)));

#if __has_builtin(__builtin_amdgcn_fdot2)
#define FDOT2(a, b, c) __builtin_amdgcn_fdot2((a), (b), (c), false)
#else
static __device__ __forceinline__ float FDOT2(h2 a, h2 b, float c) {
    return c + (float)a.x * (float)b.x + (float)a.y * (float)b.y;
}
#endif

static __device__ __forceinline__ h2 CVTPK(float a, float b) {
#if __has_builtin(__builtin_amdgcn_cvt_pkrtz)
    return __builtin_bit_cast(h2, __builtin_amdgcn_cvt_pkrtz(a, b));
#else
    h2 r; r.x = (_Float16)a; r.y = (_Float16)b; return r;
#endif
}

#if __has_builtin(__builtin_amdgcn_rcpf)
#define FRCP(x) __builtin_amdgcn_rcpf(x)
#else
#define FRCP(x) (1.0f / (x))
#endif

namespace {
constexpr int Bdim = 256;
constexpr int Rdim = 1152;
constexpr int Cdim = 10;
constexpr int Odim = 16;
constexpr int Idim = 8;
constexpr int CO   = 160;

constexpr int NCH  = 32;   // r-chunks
constexpr int ROWS = 36;   // rows per chunk
constexpr int RSUB = 4;    // rows staged per sub-step
constexpr int NSUB = 9;    // subs per chunk
constexpr int BB   = 16;   // batches per block (4 bq * 4 t)
constexpr int NT   = 320;  // 5 waves
constexpr int WELT = RSUB * Cdim * Odim * Idim;  // 5120 f16 per buffer
}

// f32 W -> f16 W16 (once per launch)
__global__ __launch_bounds__(256)
void conv_w(const float* __restrict__ W, _Float16* __restrict__ W16)
{
    const int i = blockIdx.x * 256 + threadIdx.x;
    if (i < (Rdim * Cdim * Odim * Idim) / 4) {
        const float4 v = reinterpret_cast<const float4*>(W)[i];
        h4 o = { (_Float16)v.x, (_Float16)v.y, (_Float16)v.z, (_Float16)v.w };
        reinterpret_cast<h4*>(W16)[i] = o;
    }
}

// Stage RSUB=4 W16 rows (640 x 16B granules) into linear LDS; global source
// pre-swizzled: physical granule (rr,cs,os,w) holds logical o = os*8+(w^perm).
__device__ __forceinline__ void stage2(const _Float16* __restrict__ W16,
                                       _Float16* dstbuf, int row0, int tid)
{
#pragma unroll
    for (int k = 0; k < 2; ++k) {
        const int p   = k * NT + tid;          // 0..639
        const int rr  = p / 160;
        const int rem = p - rr * 160;
        const int cs  = rem >> 4;
        const int q   = rem & 15;
        const int os  = q >> 3;
        const int w   = q & 7;
        const int o   = os * 8 + (w ^ (rr * 2 + os));
        const _Float16* src = W16 + (((size_t)(row0 + rr) * Cdim + cs) * Odim + o) * Idim;
        _Float16* d = dstbuf + (size_t)(k * NT + (tid & ~63)) * 8;  // wave-uniform; HW adds lane*16
        __builtin_amdgcn_global_load_lds((const __attribute__((address_space(1))) void*)src,
                                         (__attribute__((address_space(3))) void*)d,
                                         16, 0, 0);
    }
}

template<bool FIRST>
__global__ __launch_bounds__(NT)
void caps_iter(const float* __restrict__ x, const _Float16* __restrict__ W16,
               const float* __restrict__ Vsum, float* __restrict__ s_part)
{
    __shared__ _Float16 Wb[2][WELT];        // 2 x 10 KB
    __shared__ float    Lg[2][64 * 13];     // 2 x 3.3 KB (stride 13: conflict-free)
    __shared__ float    Vsl[BB * 164];      // 10.5 KB

    const int tid  = threadIdx.x;
    const int lane = tid & 63;
    const int oh   = lane & 1;          // o-half
    const int rl   = (lane >> 1) & 3;   // row within sub
    const int bq   = (lane >> 3) & 3;   // batch quad
    const int ch   = (lane >> 5) & 1;   // c-half
    const int cw   = tid >> 6;          // wave 0..4
    const int c    = ch * 5 + cw;

    const int bgrp  = blockIdx.x;
    const int chunk = blockIdx.y;
    const int bbase = bgrp * BB;
    const int b0    = bbase + bq * 4;   // batches b0..b0+3

    if (!FIRST) {
        for (int i = tid; i < BB * CO; i += NT) {
            const int b = i / CO;
            const int j = i - b * CO;
            Vsl[b * 164 + j] = Vsum[(size_t)bbase * CO + i];
        }
    }

    stage2(W16, &Wb[0][0], chunk * ROWS, tid);   // prologue: stage sub 0

    float s[4][8];
#pragma unroll
    for (int t = 0; t < 4; ++t)
#pragma unroll
        for (int m = 0; m < 8; ++m) s[t][m] = 0.f;

    float u[4][8];     // doubles as u_prev across the pipeline boundary
    float lsv[4];      // saved logits of previous sub
    const int perm = rl * 2 + oh;
    int buf = 0, pb = 0;

    for (int sub = 0; sub < NSUB; ++sub) {
        const int r = chunk * ROWS + sub * RSUB + rl;

        // (1) x loads: 8 x dwordx4 (stay in flight across the barrier)
        float4 xa[4], xb[4];
#pragma unroll
        for (int t = 0; t < 4; ++t) {
            const float4* xp = reinterpret_cast<const float4*>(x)
                             + ((size_t)(b0 + t) * Rdim + r) * 2;
            xa[t] = xp[0]; xb[t] = xp[1];
        }
        asm volatile("" ::: "memory");

        // (2) drain stage(sub) [2 oldest], keep 8 x-loads in flight; drain LDS ops
        asm volatile("s_waitcnt vmcnt(8) lgkmcnt(0)" ::: "memory");
        __builtin_amdgcn_s_barrier();
        asm volatile("" ::: "memory");

        // (3) stage next sub AFTER the barrier (readers of Wb[buf^1] are drained)
        if (sub + 1 < NSUB)
            stage2(W16, &Wb[buf ^ 1][0], chunk * ROWS + (sub + 1) * RSUB, tid);

        // (4) softmax of sub-1 + s accumulation of u_prev (pipelined)
        if constexpr (!FIRST) {
            if (sub > 0) {
                const int ts = ch * 2 + oh;
                const float* lp = &Lg[pb][(bq * 16 + ts * 4 + rl) * 13];
                float sum = __expf(lp[0]) + __expf(lp[1]) + __expf(lp[2])
                          + __expf(lp[3]) + __expf(lp[4]) + __expf(lp[5])
                          + __expf(lp[6]) + __expf(lp[7]) + __expf(lp[8])
                          + __expf(lp[9]);
                const float rinv = FRCP(sum);
                const float r1 = __shfl_xor(rinv, 1);
                const float r2 = __shfl_xor(rinv, 32);
                const float r3 = __shfl_xor(r1, 32);
#pragma unroll
                for (int t = 0; t < 4; ++t) {
                    const float ra = ((t & 1) == oh) ? rinv : r1;
                    const float rb = ((t & 1) == oh) ? r2 : r3;
                    const float rv = (((t >> 1) & 1) == ch) ? ra : rb;
                    const float cwt = __expf(lsv[t]) * rv;
#pragma unroll
                    for (int m = 0; m < 8; ++m) s[t][m] += cwt * u[t][m];
                }
            }
        }

        // (5) pack x to half2
        h2 xh[4][4];
#pragma unroll
        for (int t = 0; t < 4; ++t) {
            xh[t][0] = CVTPK(xa[t].x, xa[t].y);
            xh[t][1] = CVTPK(xa[t].z, xa[t].w);
            xh[t][2] = CVTPK(xb[t].x, xb[t].y);
            xh[t][3] = CVTPK(xb[t].z, xb[t].w);
        }

        // (6) u via dot2 from swizzled LDS (8 x ds_read_b128, conflict-free)
#pragma unroll
        for (int m = 0; m < 8; ++m) {
            const uint4 wv = *reinterpret_cast<const uint4*>(
                &Wb[buf][(((rl * Cdim + c) * 16) + oh * 8 + (m ^ perm)) * 8]);
            const h2 w0 = __builtin_bit_cast(h2, wv.x);
            const h2 w1 = __builtin_bit_cast(h2, wv.y);
            const h2 w2 = __builtin_bit_cast(h2, wv.z);
            const h2 w3 = __builtin_bit_cast(h2, wv.w);
#pragma unroll
            for (int t = 0; t < 4; ++t) {
                float acc = FDOT2(xh[t][0], w0, 0.f);
                acc = FDOT2(xh[t][1], w1, acc);
                acc = FDOT2(xh[t][2], w2, acc);
                u[t][m] = FDOT2(xh[t][3], w3, acc);
            }
        }

        // (7) logits -> Lg[pb^1] (non-FIRST); FIRST accumulates directly (c=0.1)
        if constexpr (!FIRST) {
#pragma unroll
            for (int t = 0; t < 4; ++t) {
                const float4* vp = reinterpret_cast<const float4*>(
                    &Vsl[(bq * 4 + t) * 164 + c * 16 + oh * 8]);
                const float4 v0 = vp[0], v1 = vp[1];
                float l = u[t][0] * v0.x + u[t][1] * v0.y + u[t][2] * v0.z + u[t][3] * v0.w
                        + u[t][4] * v1.x + u[t][5] * v1.y + u[t][6] * v1.z + u[t][7] * v1.w;
                l += __shfl_xor(l, 1);           // combine o-halves
                lsv[t] = l;
            }
            if (oh == 0) {
#pragma unroll
                for (int t = 0; t < 4; ++t)
                    Lg[pb ^ 1][(bq * 16 + t * 4 + rl) * 13 + c] = lsv[t];
            }
            pb ^= 1;
        } else {
#pragma unroll
            for (int t = 0; t < 4; ++t)
#pragma unroll
                for (int m = 0; m < 8; ++m) s[t][m] += 0.1f * u[t][m];
        }

        buf ^= 1;
    }

    // epilogue: softmax + accumulate the last sub (non-FIRST)
    if constexpr (!FIRST) {
        asm volatile("s_waitcnt lgkmcnt(0)" ::: "memory");
        __builtin_amdgcn_s_barrier();
        asm volatile("" ::: "memory");
        {
            const int ts = ch * 2 + oh;
            const float* lp = &Lg[pb][(bq * 16 + ts * 4 + rl) * 13];
            float sum = __expf(lp[0]) + __expf(lp[1]) + __expf(lp[2])
                      + __expf(lp[3]) + __expf(lp[4]) + __expf(lp[5])
                      + __expf(lp[6]) + __expf(lp[7]) + __expf(lp[8])
                      + __expf(lp[9]);
            const float rinv = FRCP(sum);
            const float r1 = __shfl_xor(rinv, 1);
            const float r2 = __shfl_xor(rinv, 32);
            const float r3 = __shfl_xor(r1, 32);
#pragma unroll
            for (int t = 0; t < 4; ++t) {
                const float ra = ((t & 1) == oh) ? rinv : r1;
                const float rb = ((t & 1) == oh) ? r2 : r3;
                const float rv = (((t >> 1) & 1) == ch) ? ra : rb;
                const float cwt = __expf(lsv[t]) * rv;
#pragma unroll
                for (int m = 0; m < 8; ++m) s[t][m] += cwt * u[t][m];
            }
        }
    }

    // reduce over rl (lane bits 1..2)
#pragma unroll
    for (int t = 0; t < 4; ++t)
#pragma unroll
        for (int m = 0; m < 8; ++m) {
            float v = s[t][m];
            v += __shfl_xor(v, 2);
            v += __shfl_xor(v, 4);
            s[t][m] = v;
        }

    if (rl == 0) {
#pragma unroll
        for (int t = 0; t < 4; ++t) {
            float* dst = s_part + (((size_t)chunk * Bdim + (b0 + t)) * CO + c * 16 + oh * 8);
            reinterpret_cast<float4*>(dst)[0] = make_float4(s[t][0], s[t][1], s[t][2], s[t][3]);
            reinterpret_cast<float4*>(dst)[1] = make_float4(s[t][4], s[t][5], s[t][6], s[t][7]);
        }
    }
}

// Sum the NCH partials, squash, then either accumulate Vsum or emit output.
template<bool LAST>
__global__ __launch_bounds__(256)
void caps_reduce(const float* __restrict__ s_part, float* __restrict__ Vsum,
                 float* __restrict__ out)
{
    const int idx = blockIdx.x * 256 + threadIdx.x;   // < 40960 = B*C*O
    float s = 0.f;
#pragma unroll 8
    for (int k = 0; k < NCH; ++k) s += s_part[(size_t)k * (Bdim * CO) + idx];

    float ssq = s * s;
    ssq += __shfl_xor(ssq, 1);
    ssq += __shfl_xor(ssq, 2);
    ssq += __shfl_xor(ssq, 4);
    ssq += __shfl_xor(ssq, 8);

    const float mag = sqrtf(ssq + 1e-8f);
    const float v = ssq / (1.f + ssq) * s / (mag + 1e-8f);

    if (LAST) out[idx] = v;
    else      Vsum[idx] += v;
}

extern "C" void kernel_launch(void* const* d_in, const int* in_sizes, int n_in,
                              void* d_out, int out_size, void* d_ws, size_t ws_size,
                              hipStream_t stream)
{
    const float* x = (const float*)d_in[0];   // [256,1152,8]
    const float* W = (const float*)d_in[1];   // [1152,10,16,8]
    float* out = (float*)d_out;               // [256,10,16]

    float* s_part = (float*)d_ws;                       // 32*256*160 f32
    float* Vsum   = s_part + (size_t)NCH * Bdim * CO;   // 256*160 f32
    _Float16* W16 = (_Float16*)(Vsum + Bdim * CO);      // 1152*10*16*8 f16

    (void)hipMemsetAsync(Vsum, 0, (size_t)Bdim * CO * sizeof(float), stream);

    conv_w<<<dim3((Rdim * Cdim * Odim * Idim / 4 + 255) / 256), dim3(256), 0, stream>>>(W, W16);

    const dim3 gi(Bdim / BB, NCH);
    const dim3 bi(NT);
    const dim3 gr((Bdim * CO) / 256);
    const dim3 br(256);

    // it 0
    caps_iter<true><<<gi, bi, 0, stream>>>(x, W16, Vsum, s_part);
    caps_reduce<false><<<gr, br, 0, stream>>>(s_part, Vsum, out);
    // it 1
    caps_iter<false><<<gi, bi, 0, stream>>>(x, W16, Vsum, s_part);
    caps_reduce<false><<<gr, br, 0, stream>>>(s_part, Vsum, out);
    // it 2 (final -> d_out)
    caps_iter<false><<<gi, bi, 0, stream>>>(x, W16, Vsum, s_part);
    caps_reduce<true><<<gr, br, 0, stream>>>(s_part, Vsum, out);
}

// Round 7
// 91.020 us; speedup vs baseline: 3.5173x; 1.3002x over previous
//
#include <hip/hip_runtime.h>
#include <math.h>

// DigitCaps dynamic routing, B=256 R=1152 C=10 OUT=16 IN=8, fp32 in/out.
// Identity: b_ij(t) = dot(u_hat, Vsum), Vsum = sum of previous v iterates ->
// never store b_ij or u_hat; recompute u_hat each iteration from W (f16).
//
// Barrier-free iter kernel: wave = 8 batches x 8 o-groups (2 o's each); each
// thread owns all 10 c's for its (b,r,og) -> softmax is thread-local after a
// 3-step shfl_xor over the og lanes. W rows staged per-wave into private LDS
// double-buffer via linear global_load_lds (no swizzle needed; ds_read pattern
// is 2-way + broadcast = conflict-free). Only per-wave vmcnt(0), no barriers
// in the main loop. 4 waves/block cover 4 r-chunks; in-block LDS reduce.
// No memset: caps_reduce mode 0 WRITES Vsum (so no zero-init fill kernel).
//
// ws: s_part[16][256][160] f32 (2.62 MB) + Vsum[256][160] f32 (0.16 MB)
//     + W16 (2.95 MB f16) + X16 (4.72 MB f16) = 10.45 MB

typedef _Float16 h2 __attribute__((ext_vector_type(2)));
typedef _Float16 h4 __attribute__((ext_vector_type(4)));

#if __has_builtin(__builtin_amdgcn_fdot2)
#define FDOT2(a, b, c) __builtin_amdgcn_fdot2((a), (b), (c), false)
#else
static __device__ __forceinline__ float FDOT2(h2 a, h2 b, float c) {
    return c + (float)a.x * (float)b.x + (float)a.y * (float)b.y;
}
#endif

#if __has_builtin(__builtin_amdgcn_rcpf)
#define FRCP(x) __builtin_amdgcn_rcpf(x)
#else
#define FRCP(x) (1.0f / (x))
#endif

#define BCH2(u) __builtin_bit_cast(h2, (u))

namespace {
constexpr int Bdim = 256;
constexpr int Rdim = 1152;
constexpr int Cdim = 10;
constexpr int Odim = 16;
constexpr int Idim = 8;
constexpr int CO   = 160;

constexpr int NRC   = 64;    // r-chunks (one per wave)
constexpr int RPC   = 18;    // rows per chunk
constexpr int NPAIR = 9;     // row-pairs per chunk
constexpr int NSP   = 16;    // s_part slices (= NRC / 4 waves-per-block)
constexpr int WROW  = Cdim * Odim * Idim;       // 1280 f16 per W row
constexpr int REDP  = 162;   // padded f32 row stride in reduce buffer
}

// f32 -> f16 for W and x (once per launch). Exact grid: 958464/256 = 3744.
__global__ __launch_bounds__(256)
void conv_wx(const float* __restrict__ W, const float* __restrict__ x,
             _Float16* __restrict__ W16, _Float16* __restrict__ X16)
{
    constexpr int NW4 = Rdim * Cdim * Odim * Idim / 4;   // 368640
    constexpr int NX4 = Bdim * Rdim * Idim / 4;          // 589824
    const int i = blockIdx.x * 256 + threadIdx.x;
    if (i < NW4) {
        const float4 v = reinterpret_cast<const float4*>(W)[i];
        h4 o = { (_Float16)v.x, (_Float16)v.y, (_Float16)v.z, (_Float16)v.w };
        reinterpret_cast<h4*>(W16)[i] = o;
    } else if (i < NW4 + NX4) {
        const int j = i - NW4;
        const float4 v = reinterpret_cast<const float4*>(x)[j];
        h4 o = { (_Float16)v.x, (_Float16)v.y, (_Float16)v.z, (_Float16)v.w };
        reinterpret_cast<h4*>(X16)[j] = o;
    }
}

// Stage one W row-pair (2560 f16 = 5 KB) linearly into this wave's LDS buffer.
__device__ __forceinline__ void stagepair(const _Float16* __restrict__ src,
                                          _Float16* dst, int lane)
{
#pragma unroll
    for (int k = 0; k < 5; ++k) {
        const _Float16* s = src + (size_t)(k * 64 + lane) * 8;   // 16B granule
        _Float16* d = dst + k * 512;                             // wave-uniform
        __builtin_amdgcn_global_load_lds((const __attribute__((address_space(1))) void*)s,
                                         (__attribute__((address_space(3))) void*)d,
                                         16, 0, 0);
    }
}

template<bool FIRST>
__global__ __launch_bounds__(256)
void caps_iter(const _Float16* __restrict__ X16, const _Float16* __restrict__ W16,
               const float* __restrict__ Vsum, float* __restrict__ s_part)
{
    __shared__ _Float16 Wstage[4][2][2560];   // 40 KB; reused as reduce buffer

    const int tid  = threadIdx.x;
    const int wv   = tid >> 6;
    const int lane = tid & 63;
    const int og   = lane & 7;          // o-group: o = og*2, og*2+1
    const int bl   = lane >> 3;         // batch within group

    const int bgroup = blockIdx.x;      // 0..31
    const int rcq    = blockIdx.y;      // 0..15
    const int r0     = (rcq * 4 + wv) * RPC;
    const int b      = bgroup * 8 + bl;

    // v (= Vsum) registers: v[b][c][og*2 .. +1]
    float va[Cdim], vb[Cdim];
    if constexpr (!FIRST) {
#pragma unroll
        for (int c = 0; c < Cdim; ++c) {
            const float2 vv = *reinterpret_cast<const float2*>(
                Vsum + (size_t)b * CO + c * Odim + og * 2);
            va[c] = vv.x; vb[c] = vv.y;
        }
    }

    float s0[Cdim], s1[Cdim];
#pragma unroll
    for (int c = 0; c < Cdim; ++c) { s0[c] = 0.f; s1[c] = 0.f; }

    const _Float16* Wr = W16 + (size_t)r0 * WROW;
    _Float16* const st0 = &Wstage[wv][0][0];
    _Float16* const st1 = &Wstage[wv][1][0];

    stagepair(Wr, st0, lane);                 // prologue: pair 0
    uint4 xc0, xc1;
    {
        const uint4* xp = reinterpret_cast<const uint4*>(
            X16 + ((size_t)b * Rdim + r0) * Idim);
        xc0 = xp[0]; xc1 = xp[1];
    }

    for (int p = 0; p < NPAIR; ++p) {
        // wait: this pair's stage + x arrived (the only outstanding VMEM)
        asm volatile("s_waitcnt vmcnt(0)" ::: "memory");

        const _Float16* stcur = (p & 1) ? st1 : st0;
        _Float16* stnxt = (p & 1) ? st0 : st1;
        uint4 xn0, xn1;
        if (p + 1 < NPAIR) {
            stagepair(Wr + (size_t)(p + 1) * 2560, stnxt, lane);
            const uint4* xq = reinterpret_cast<const uint4*>(
                X16 + ((size_t)b * Rdim + r0 + (p + 1) * 2) * Idim);
            xn0 = xq[0]; xn1 = xq[1];
        }

#pragma unroll
        for (int rl = 0; rl < 2; ++rl) {
            const uint4 xv = rl ? xc1 : xc0;
            const h2 x0 = BCH2(xv.x), x1 = BCH2(xv.y), x2 = BCH2(xv.z), x3 = BCH2(xv.w);

            float u0[Cdim], u1[Cdim];
#pragma unroll
            for (int c = 0; c < Cdim; ++c) {
                const uint4* wp = reinterpret_cast<const uint4*>(
                    stcur + rl * WROW + (c * Odim + og * 2) * Idim);
                const uint4 w0 = wp[0], w1 = wp[1];
                float a = FDOT2(BCH2(w0.x), x0, 0.f);
                a = FDOT2(BCH2(w0.y), x1, a);
                a = FDOT2(BCH2(w0.z), x2, a);
                u0[c] = FDOT2(BCH2(w0.w), x3, a);
                float d = FDOT2(BCH2(w1.x), x0, 0.f);
                d = FDOT2(BCH2(w1.y), x1, d);
                d = FDOT2(BCH2(w1.z), x2, d);
                u1[c] = FDOT2(BCH2(w1.w), x3, d);
            }

            if constexpr (FIRST) {
#pragma unroll
                for (int c = 0; c < Cdim; ++c) {
                    s0[c] += 0.1f * u0[c];    // softmax of zeros over C=10
                    s1[c] += 0.1f * u1[c];
                }
            } else {
                float e[Cdim];
                float sum = 0.f;
#pragma unroll
                for (int c = 0; c < Cdim; ++c) {
                    float l = u0[c] * va[c] + u1[c] * vb[c];
                    l += __shfl_xor(l, 1);    // combine over og lanes
                    l += __shfl_xor(l, 2);
                    l += __shfl_xor(l, 4);
                    e[c] = __expf(l);         // |l| <~ 30: f32-safe, no max pass
                    sum += e[c];
                }
                const float rinv = FRCP(sum);
#pragma unroll
                for (int c = 0; c < Cdim; ++c) {
                    const float cw = e[c] * rinv;
                    s0[c] += cw * u0[c];
                    s1[c] += cw * u1[c];
                }
            }
        }

        if (p + 1 < NPAIR) { xc0 = xn0; xc1 = xn1; }
    }

    // ---- in-block reduce over the 4 waves' r-chunks (reuse Wstage as f32 buf)
    __syncthreads();
    float* red = reinterpret_cast<float*>(&Wstage[0][0][0]);   // [4][8][REDP]
    {
        float* myrow = red + (wv * 8 + bl) * REDP + og * 2;
#pragma unroll
        for (int c = 0; c < Cdim; ++c)
            *reinterpret_cast<float2*>(myrow + c * Odim) = make_float2(s0[c], s1[c]);
    }
    __syncthreads();
#pragma unroll
    for (int k = 0; k < 5; ++k) {
        const int j  = k * 256 + tid;        // 0..1279
        const int b2 = j / CO;
        const int co = j - b2 * CO;
        const int o  = b2 * REDP + co;
        const float t = red[o] + red[8 * REDP + o]
                      + red[16 * REDP + o] + red[24 * REDP + o];
        s_part[((size_t)rcq * Bdim + bgroup * 8 + b2) * CO + co] = t;
    }
}

// Sum the NSP partials, squash; MODE 0: Vsum = v (it0, replaces memset),
// MODE 1: Vsum += v, MODE 2: out = v.
template<int MODE>
__global__ __launch_bounds__(256)
void caps_reduce(const float* __restrict__ s_part, float* __restrict__ Vsum,
                 float* __restrict__ out)
{
    const int idx = blockIdx.x * 256 + threadIdx.x;   // < 40960 = B*C*O
    float s = 0.f;
#pragma unroll
    for (int k = 0; k < NSP; ++k) s += s_part[(size_t)k * (Bdim * CO) + idx];

    float ssq = s * s;
    ssq += __shfl_xor(ssq, 1);
    ssq += __shfl_xor(ssq, 2);
    ssq += __shfl_xor(ssq, 4);
    ssq += __shfl_xor(ssq, 8);

    const float mag = sqrtf(ssq + 1e-8f);
    const float v = ssq / (1.f + ssq) * s / (mag + 1e-8f);

    if constexpr (MODE == 2) out[idx] = v;
    else if constexpr (MODE == 1) Vsum[idx] += v;
    else Vsum[idx] = v;
}

extern "C" void kernel_launch(void* const* d_in, const int* in_sizes, int n_in,
                              void* d_out, int out_size, void* d_ws, size_t ws_size,
                              hipStream_t stream)
{
    const float* x = (const float*)d_in[0];   // [256,1152,8]
    const float* W = (const float*)d_in[1];   // [1152,10,16,8]
    float* out = (float*)d_out;               // [256,10,16]

    float* s_part = (float*)d_ws;                           // 16*256*160 f32
    float* Vsum   = s_part + (size_t)NSP * Bdim * CO;       // 256*160 f32
    _Float16* W16 = (_Float16*)(Vsum + Bdim * CO);          // 1474560 f16
    _Float16* X16 = W16 + (size_t)Rdim * Cdim * Odim * Idim;// 2359296 f16

    conv_wx<<<dim3(3744), dim3(256), 0, stream>>>(W, x, W16, X16);

    const dim3 gi(Bdim / 8, NSP);    // (32, 16) = 512 blocks, 4 waves each
    const dim3 bi(256);
    const dim3 gr((Bdim * CO) / 256);
    const dim3 br(256);

    // it 0
    caps_iter<true><<<gi, bi, 0, stream>>>(X16, W16, Vsum, s_part);
    caps_reduce<0><<<gr, br, 0, stream>>>(s_part, Vsum, out);
    // it 1
    caps_iter<false><<<gi, bi, 0, stream>>>(X16, W16, Vsum, s_part);
    caps_reduce<1><<<gr, br, 0, stream>>>(s_part, Vsum, out);
    // it 2 (final -> d_out)
    caps_iter<false><<<gi, bi, 0, stream>>>(X16, W16, Vsum, s_part);
    caps_reduce<2><<<gr, br, 0, stream>>>(s_part, Vsum, out);
}